// Round 5
// baseline (1111.491 us; speedup 1.0000x reference)
//
#include <hip/hip_runtime.h>

typedef short bf16x8 __attribute__((ext_vector_type(8)));
typedef float f32x4 __attribute__((ext_vector_type(4)));

constexpr int NB1    = 131073;   // num_bonds + 1 (row 131072 = zero sentinel)
constexpr int SENT   = 131072;
constexpr int NATOMS = 65536;
constexpr int AFD    = 133;
constexpr int CFD    = 147;
constexpr int DH     = 300;
constexpr int GFD    = 2048;
constexpr int NMOLS  = 4096;
constexpr int OUTD   = DH + GFD; // 2348
constexpr int HS     = 320;      // h row stride (bf16) = padded N
constexpr int KP1    = 160;      // padded CFD / AFD
constexpr int KP2    = 320;      // padded DH

__device__ __forceinline__ unsigned short f2b(float f) {
    unsigned u = __float_as_uint(f);
    u += 0x7fffu + ((u >> 16) & 1u);
    return (unsigned short)(u >> 16);
}
__device__ __forceinline__ unsigned pairsum4(unsigned a, unsigned b, unsigned c, unsigned d) {
    float lo = __uint_as_float(a << 16) + __uint_as_float(b << 16) +
               __uint_as_float(c << 16) + __uint_as_float(d << 16);
    float hi = __uint_as_float(a & 0xffff0000u) + __uint_as_float(b & 0xffff0000u) +
               __uint_as_float(c & 0xffff0000u) + __uint_as_float(d & 0xffff0000u);
    return ((unsigned)f2b(hi) << 16) | (unsigned)f2b(lo);
}
__device__ __forceinline__ bf16x8 asbf(uint4 u) {
    union { uint4 u; bf16x8 b; } c; c.u = u; return c.b;
}

// ==== bond GEMM, barrier-free: wave = 16 rows x 320 cols ====
// hdst = relu( fini@WiP^T  [+ (gather-sum_4 hsrc[mapping]) @ WhP^T] )
__global__ __launch_bounds__(256, 3) void bond_gemm(
    const float* __restrict__ fini,            // [NB1][147] fp32
    const unsigned short* __restrict__ finiB,  // [NB1][160] bf16 (if useB)
    const unsigned short* __restrict__ hsrc,   // [NB1][HS] bf16
    const int* __restrict__ mapping,           // [NB1][4]
    const unsigned short* __restrict__ WiP,    // [320][160] bf16
    const unsigned short* __restrict__ WhP,    // [320][320] bf16
    unsigned short* __restrict__ hdst,         // [NB1][HS] bf16
    int do_msg, int useB)
{
    const int tid  = threadIdx.x;
    const int wv   = tid >> 6;
    const int lane = tid & 63;
    const int ml   = lane & 15;        // A row within tile / B col / C col
    const int kh   = lane >> 4;        // k-segment 0..3 (elems kh*8..kh*8+7)
    const int m0   = blockIdx.x * 64 + wv * 16;
    const int mrow = m0 + ml;
    const int mrowc = mrow < NB1 ? mrow : SENT;   // clamp loads to valid sentinel row

    f32x4 acc[20];
#pragma unroll
    for (int nt = 0; nt < 20; ++nt) acc[nt] = (f32x4){0.f, 0.f, 0.f, 0.f};

    // ---- phase 1: K=160 over fini with WiP ----
    if (useB) {
        const unsigned short* fb = finiB + (size_t)mrowc * KP1 + kh * 8;
#pragma unroll
        for (int c = 0; c < 5; ++c) {
            bf16x8 af = *(const bf16x8*)(fb + c * 32);
            const unsigned short* bp = WiP + ml * KP1 + c * 32 + kh * 8;
#pragma unroll
            for (int nt = 0; nt < 20; ++nt) {
                bf16x8 bf = *(const bf16x8*)(bp + nt * 16 * KP1);
                acc[nt] = __builtin_amdgcn_mfma_f32_16x16x32_bf16(af, bf, acc[nt], 0, 0, 0);
            }
        }
    } else {
        const float* fp = fini + (size_t)mrowc * CFD;
#pragma unroll
        for (int c = 0; c < 5; ++c) {
            union { short s[8]; bf16x8 x; } u;
#pragma unroll
            for (int j = 0; j < 8; ++j) {
                int k = c * 32 + kh * 8 + j;
                u.s[j] = (short)f2b(k < CFD ? fp[k] : 0.f);
            }
            const unsigned short* bp = WiP + ml * KP1 + c * 32 + kh * 8;
#pragma unroll
            for (int nt = 0; nt < 20; ++nt) {
                bf16x8 bf = *(const bf16x8*)(bp + nt * 16 * KP1);
                acc[nt] = __builtin_amdgcn_mfma_f32_16x16x32_bf16(u.x, bf, acc[nt], 0, 0, 0);
            }
        }
    }

    // ---- phase 2: K=320 over gather-sum(h) with WhP; gathers land directly in A-frag regs ----
    if (do_msg) {
        int4 mp = *(const int4*)(mapping + (size_t)mrowc * 4);
        int i0 = mp.x < 0 ? SENT : mp.x;
        int i1 = mp.y < 0 ? SENT : mp.y;
        int i2 = mp.z < 0 ? SENT : mp.z;
        int i3 = mp.w < 0 ? SENT : mp.w;
        const unsigned short* g0 = hsrc + (size_t)i0 * HS + kh * 8;
        const unsigned short* g1 = hsrc + (size_t)i1 * HS + kh * 8;
        const unsigned short* g2 = hsrc + (size_t)i2 * HS + kh * 8;
        const unsigned short* g3 = hsrc + (size_t)i3 * HS + kh * 8;

        uint4 ga = *(const uint4*)g0;
        uint4 gb = *(const uint4*)g1;
        uint4 gc = *(const uint4*)g2;
        uint4 gd = *(const uint4*)g3;
#pragma unroll
        for (int c = 0; c < 10; ++c) {
            uint4 na, nb, nc2, nd;
            if (c < 9) {
                na  = *(const uint4*)(g0 + (c + 1) * 32);
                nb  = *(const uint4*)(g1 + (c + 1) * 32);
                nc2 = *(const uint4*)(g2 + (c + 1) * 32);
                nd  = *(const uint4*)(g3 + (c + 1) * 32);
            }
            uint4 o;
            o.x = pairsum4(ga.x, gb.x, gc.x, gd.x);
            o.y = pairsum4(ga.y, gb.y, gc.y, gd.y);
            o.z = pairsum4(ga.z, gb.z, gc.z, gd.z);
            o.w = pairsum4(ga.w, gb.w, gc.w, gd.w);
            bf16x8 af = asbf(o);
            const unsigned short* bp = WhP + ml * KP2 + c * 32 + kh * 8;
#pragma unroll
            for (int nt = 0; nt < 20; ++nt) {
                bf16x8 bf = *(const bf16x8*)(bp + nt * 16 * KP2);
                acc[nt] = __builtin_amdgcn_mfma_f32_16x16x32_bf16(af, bf, acc[nt], 0, 0, 0);
            }
            if (c < 9) { ga = na; gb = nb; gc = nc2; gd = nd; }
        }
    }

    // ---- epilogue: C[row=kh*4+reg][col=nt*16+ml]; relu -> bf16 ----
#pragma unroll
    for (int nt = 0; nt < 20; ++nt) {
        int n = nt * 16 + ml;
#pragma unroll
        for (int reg = 0; reg < 4; ++reg) {
            int m = m0 + kh * 4 + reg;
            if (m < NB1) {
                float v = acc[nt][reg];
                hdst[(size_t)m * HS + n] = f2b(v > 0.f ? v : 0.f);
            }
        }
    }
}

// ==== atom GEMM + fused molecule mean, barrier-free: wave = 1 molecule (16 atoms) ====
__global__ __launch_bounds__(256, 3) void atom_gemm(
    const float* __restrict__ atomf,           // [NATOMS][133] fp32
    const unsigned short* __restrict__ hsrc,   // [NB1][HS] bf16
    const int* __restrict__ a2b,               // [NATOMS][4]
    const unsigned short* __restrict__ WoA,    // [320][160] bf16 (Wo cols 0..132)
    const unsigned short* __restrict__ WoB,    // [320][320] bf16 (Wo cols 133..432)
    const float* __restrict__ bo,              // [300]
    float* __restrict__ out)                   // [NMOLS][OUTD]
{
    const int tid  = threadIdx.x;
    const int wv   = tid >> 6;
    const int lane = tid & 63;
    const int ml   = lane & 15;
    const int kh   = lane >> 4;
    const int m0   = blockIdx.x * 64 + wv * 16;
    const int arow = m0 + ml;

    f32x4 acc[20];
#pragma unroll
    for (int nt = 0; nt < 20; ++nt) acc[nt] = (f32x4){0.f, 0.f, 0.f, 0.f};

    // ---- phase A: atomf (fp32, K=133 pad 160) @ WoA ----
    {
        const float* fp = atomf + (size_t)arow * AFD;
#pragma unroll
        for (int c = 0; c < 5; ++c) {
            union { short s[8]; bf16x8 x; } u;
#pragma unroll
            for (int j = 0; j < 8; ++j) {
                int k = c * 32 + kh * 8 + j;
                u.s[j] = (short)f2b(k < AFD ? fp[k] : 0.f);
            }
            const unsigned short* bp = WoA + ml * KP1 + c * 32 + kh * 8;
#pragma unroll
            for (int nt = 0; nt < 20; ++nt) {
                bf16x8 bf = *(const bf16x8*)(bp + nt * 16 * KP1);
                acc[nt] = __builtin_amdgcn_mfma_f32_16x16x32_bf16(u.x, bf, acc[nt], 0, 0, 0);
            }
        }
    }

    // ---- phase B: gather-sum(h) (K=320) @ WoB ----
    {
        int4 mp = *(const int4*)(a2b + (size_t)arow * 4);
        int i0 = mp.x < 0 ? SENT : mp.x;
        int i1 = mp.y < 0 ? SENT : mp.y;
        int i2 = mp.z < 0 ? SENT : mp.z;
        int i3 = mp.w < 0 ? SENT : mp.w;
        const unsigned short* g0 = hsrc + (size_t)i0 * HS + kh * 8;
        const unsigned short* g1 = hsrc + (size_t)i1 * HS + kh * 8;
        const unsigned short* g2 = hsrc + (size_t)i2 * HS + kh * 8;
        const unsigned short* g3 = hsrc + (size_t)i3 * HS + kh * 8;

        uint4 ga = *(const uint4*)g0;
        uint4 gb = *(const uint4*)g1;
        uint4 gc = *(const uint4*)g2;
        uint4 gd = *(const uint4*)g3;
#pragma unroll
        for (int c = 0; c < 10; ++c) {
            uint4 na, nb, nc2, nd;
            if (c < 9) {
                na  = *(const uint4*)(g0 + (c + 1) * 32);
                nb  = *(const uint4*)(g1 + (c + 1) * 32);
                nc2 = *(const uint4*)(g2 + (c + 1) * 32);
                nd  = *(const uint4*)(g3 + (c + 1) * 32);
            }
            uint4 o;
            o.x = pairsum4(ga.x, gb.x, gc.x, gd.x);
            o.y = pairsum4(ga.y, gb.y, gc.y, gd.y);
            o.z = pairsum4(ga.z, gb.z, gc.z, gd.z);
            o.w = pairsum4(ga.w, gb.w, gc.w, gd.w);
            bf16x8 af = asbf(o);
            const unsigned short* bp = WoB + ml * KP2 + c * 32 + kh * 8;
#pragma unroll
            for (int nt = 0; nt < 20; ++nt) {
                bf16x8 bf = *(const bf16x8*)(bp + nt * 16 * KP2);
                acc[nt] = __builtin_amdgcn_mfma_f32_16x16x32_bf16(af, bf, acc[nt], 0, 0, 0);
            }
            if (c < 9) { ga = na; gb = nb; gc = nc2; gd = nd; }
        }
    }

    // ---- epilogue: bias + relu + mean over the wave's 16 atoms (= 1 molecule) ----
    const int mol = blockIdx.x * 4 + wv;
#pragma unroll
    for (int nt = 0; nt < 20; ++nt) {
        int n = nt * 16 + ml;
        float bias = (n < DH) ? bo[n] : 0.f;
        float s = 0.f;
#pragma unroll
        for (int reg = 0; reg < 4; ++reg) {
            float v = acc[nt][reg] + bias;
            s += (v > 0.f ? v : 0.f);
        }
        s += __shfl_down(s, 32, 64);
        s += __shfl_down(s, 16, 64);
        if (kh == 0 && n < DH) out[(size_t)mol * OUTD + n] = s * (1.f / 16.f);
    }
}

// ---- fini fp32 -> padded bf16 [NB1][160] ----
__global__ void prep_fini(const float* __restrict__ fini, unsigned short* __restrict__ finiB) {
    int t = blockIdx.x * blockDim.x + threadIdx.x;
    if (t >= NB1 * 20) return;
    int row = t / 20, g = t % 20;
    const float* src = fini + (size_t)row * CFD;
    union { unsigned short s[8]; uint4 u; } o;
#pragma unroll
    for (int j = 0; j < 8; ++j) {
        int k = g * 8 + j;
        o.s[j] = (k < CFD) ? f2b(src[k]) : (unsigned short)0;
    }
    *(uint4*)(finiB + (size_t)row * KP1 + g * 8) = o.u;
}

// ---- weight prep: fp32 -> padded bf16 ----
__global__ void prep_w(const float* __restrict__ Wi, const float* __restrict__ Wh,
                       const float* __restrict__ Wo, unsigned short* __restrict__ wb) {
    int t = blockIdx.x * blockDim.x + threadIdx.x;
    if (t >= 307200) return;
    float v = 0.f;
    if (t < 51200) {                       // WiP [320][160]
        int n = t / 160, k = t % 160;
        if (n < DH && k < CFD) v = Wi[n * CFD + k];
    } else if (t < 153600) {               // WhP [320][320]
        int q = t - 51200; int n = q / 320, k = q % 320;
        if (n < DH && k < DH) v = Wh[n * DH + k];
    } else if (t < 204800) {               // WoA [320][160]
        int q = t - 153600; int n = q / 160, k = q % 160;
        if (n < DH && k < AFD) v = Wo[n * 433 + k];
    } else {                               // WoB [320][320]
        int q = t - 204800; int n = q / 320, k = q % 320;
        if (n < DH && k < DH) v = Wo[n * 433 + AFD + k];
    }
    wb[t] = f2b(v);
}

// ---- copy global features: out[mol][300:2348] = gf[mol] ----
__global__ void copy_gf(const float4* __restrict__ gf, float* __restrict__ out) {
    int t = blockIdx.x * blockDim.x + threadIdx.x;
    if (t >= NMOLS * (GFD / 4)) return;
    int mol = t >> 9;
    int g4 = t & 511;
    float4 v = gf[t];
    *(float4*)(out + (size_t)mol * OUTD + DH + g4 * 4) = v;
}

extern "C" void kernel_launch(void* const* d_in, const int* in_sizes, int n_in,
                              void* d_out, int out_size, void* d_ws, size_t ws_size,
                              hipStream_t stream) {
    const float* atomf   = (const float*)d_in[0];
    const float* fini    = (const float*)d_in[1];
    const int*   a2b     = (const int*)d_in[2];
    const int*   mapping = (const int*)d_in[3];
    const float* gf      = (const float*)d_in[4];
    const float* W_i     = (const float*)d_in[5];
    const float* W_h     = (const float*)d_in[6];
    const float* W_o     = (const float*)d_in[7];
    const float* b_o     = (const float*)d_in[8];
    float* out = (float*)d_out;

    // ws: h_a (83.9 MB) | h_b (83.9 MB) | weights (0.61 MB) [| finiB 41.9 MB if room]
    char* ws = (char*)d_ws;
    size_t SH = (size_t)NB1 * HS * sizeof(unsigned short);
    size_t SW = 307200 * sizeof(unsigned short);
    size_t SF = (size_t)NB1 * KP1 * sizeof(unsigned short);
    unsigned short* h_a = (unsigned short*)ws;
    unsigned short* h_b = (unsigned short*)(ws + SH);
    unsigned short* wb  = (unsigned short*)(ws + 2 * SH);
    unsigned short* finiB = (unsigned short*)(ws + 2 * SH + SW);
    unsigned short* WiP = wb;
    unsigned short* WhP = wb + 51200;
    unsigned short* WoA = wb + 153600;
    unsigned short* WoB = wb + 204800;
    int useB = (ws_size >= 2 * SH + SW + SF) ? 1 : 0;

    dim3 blk(256);
    prep_w<<<1200, blk, 0, stream>>>(W_i, W_h, W_o, wb);
    if (useB) prep_fini<<<(NB1 * 20 + 255) / 256, blk, 0, stream>>>(fini, finiB);
    bond_gemm<<<2049, blk, 0, stream>>>(fini, finiB, h_a, mapping, WiP, WhP, h_a, 0, useB);
    bond_gemm<<<2049, blk, 0, stream>>>(fini, finiB, h_a, mapping, WiP, WhP, h_b, 1, useB);
    bond_gemm<<<2049, blk, 0, stream>>>(fini, finiB, h_b, mapping, WiP, WhP, h_a, 1, useB);
    atom_gemm<<<1024, blk, 0, stream>>>(atomf, h_a, a2b, WoA, WoB, b_o, out);
    copy_gf<<<NMOLS * (GFD / 4) / 256, blk, 0, stream>>>((const float4*)gf, out);
}

// Round 6
// 612.515 us; speedup vs baseline: 1.8146x; 1.8146x over previous
//
#include <hip/hip_runtime.h>

typedef short bf16x8 __attribute__((ext_vector_type(8)));
typedef float f32x4 __attribute__((ext_vector_type(4)));

constexpr int NB1    = 131073;   // num_bonds + 1 (row 131072 = zero sentinel)
constexpr int SENT   = 131072;
constexpr int NATOMS = 65536;
constexpr int AFD    = 133;
constexpr int CFD    = 147;
constexpr int DH     = 300;
constexpr int GFD    = 2048;
constexpr int NMOLS  = 4096;
constexpr int OUTD   = DH + GFD; // 2348
constexpr int HS     = 320;      // h/y/inp row stride (bf16) = padded N
constexpr int KP1    = 160;      // padded CFD / AFD
constexpr int KP2    = 320;      // padded DH
constexpr int KPC    = 480;      // padded concat K for atom GEMM (160 + 320)

__device__ __forceinline__ unsigned short f2b(float f) {
    unsigned u = __float_as_uint(f);
    u += 0x7fffu + ((u >> 16) & 1u);
    return (unsigned short)(u >> 16);
}
__device__ __forceinline__ float blo(unsigned x) { return __uint_as_float(x << 16); }
__device__ __forceinline__ float bhi(unsigned x) { return __uint_as_float(x & 0xffff0000u); }
__device__ __forceinline__ unsigned pk2(float hi, float lo) {
    return ((unsigned)f2b(hi) << 16) | (unsigned)f2b(lo);
}
__device__ __forceinline__ unsigned pairsum4(unsigned a, unsigned b, unsigned c, unsigned d) {
    float lo = blo(a) + blo(b) + blo(c) + blo(d);
    float hi = bhi(a) + bhi(b) + bhi(c) + bhi(d);
    return pk2(hi, lo);
}
__device__ __forceinline__ unsigned relu_pk(unsigned u) {
    unsigned lo = (u & 0x8000u) ? 0u : (u & 0xFFFFu);
    unsigned hi = (u & 0x80000000u) ? 0u : (u & 0xFFFF0000u);
    return lo | hi;
}
__device__ __forceinline__ uint4 relu4(uint4 v) {
    v.x = relu_pk(v.x); v.y = relu_pk(v.y); v.z = relu_pk(v.z); v.w = relu_pk(v.w);
    return v;
}
__device__ __forceinline__ bf16x8 asbf(uint4 u) {
    union { uint4 u; bf16x8 b; } c; c.u = u; return c.b;
}

// 20 MFMAs: A frags from LDS (layout [kh 4][row 64][8]), B from registers
__device__ __forceinline__ void mfma_step(const short* __restrict__ A, const uint4 (&B)[5],
                                          int ml, int kl, f32x4 (&acc)[4][5]) {
    bf16x8 af[4];
#pragma unroll
    for (int mt = 0; mt < 4; ++mt)
        af[mt] = *(const bf16x8*)&A[(kl * 64 + mt * 16 + ml) * 8];
#pragma unroll
    for (int mt = 0; mt < 4; ++mt)
#pragma unroll
        for (int nt = 0; nt < 5; ++nt)
            acc[mt][nt] = __builtin_amdgcn_mfma_f32_16x16x32_bf16(af[mt], asbf(B[nt]), acc[mt][nt], 0, 0, 0);
}

// ===================== PRIMARY PATH =====================

// ---- gemm1: inp = fini @ WiP^T, raw (pre-relu) bf16, padded to 320 cols ----
__global__ __launch_bounds__(256, 3) void gemm1(
    const float* __restrict__ fini,          // [NB1][147] fp32
    const unsigned short* __restrict__ WiP,  // [320][160] bf16
    unsigned short* __restrict__ inp)        // [NB1][320] bf16 raw
{
    __shared__ __align__(16) short As[2][4 * 64 * 8];
    const int tid = threadIdx.x, w = tid >> 6, lane = tid & 63;
    const int ml = lane & 15, kl = lane >> 4;
    const int sr = tid & 63, seg = tid >> 6;
    const int m0 = blockIdx.x * 64;
    const bool mok = (m0 + sr) < NB1;
    const float* fp = fini + (size_t)(mok ? m0 + sr : SENT) * CFD;
    const unsigned short* bp = WiP + (size_t)(w * 80 + ml) * KP1 + kl * 8;

    f32x4 acc[4][5];
#pragma unroll
    for (int mt = 0; mt < 4; ++mt)
#pragma unroll
        for (int nt = 0; nt < 5; ++nt) acc[mt][nt] = (f32x4){0.f, 0.f, 0.f, 0.f};

    {
        union { short s[8]; uint4 u; } st;
#pragma unroll
        for (int j = 0; j < 8; ++j) {
            int k = seg * 8 + j;
            st.s[j] = (short)f2b((mok && k < CFD) ? fp[k] : 0.f);
        }
        *(uint4*)&As[0][(seg * 64 + sr) * 8] = st.u;
    }
    uint4 Bcur[5];
#pragma unroll
    for (int nt = 0; nt < 5; ++nt) Bcur[nt] = *(const uint4*)(bp + nt * 16 * KP1);
    __syncthreads();

    for (int c = 0; c < 5; ++c) {
        const int cn = c + 1;
        float vn[8]; uint4 Bn[5];
        if (cn < 5) {
#pragma unroll
            for (int j = 0; j < 8; ++j) {
                int k = cn * 32 + seg * 8 + j;
                vn[j] = (mok && k < CFD) ? fp[k] : 0.f;
            }
#pragma unroll
            for (int nt = 0; nt < 5; ++nt) Bn[nt] = *(const uint4*)(bp + cn * 32 + nt * 16 * KP1);
        }
        mfma_step(As[c & 1], Bcur, ml, kl, acc);
        if (cn < 5) {
            union { short s[8]; uint4 u; } st;
#pragma unroll
            for (int j = 0; j < 8; ++j) st.s[j] = (short)f2b(vn[j]);
            *(uint4*)&As[cn & 1][(seg * 64 + sr) * 8] = st.u;
#pragma unroll
            for (int nt = 0; nt < 5; ++nt) Bcur[nt] = Bn[nt];
        }
        __syncthreads();
    }
#pragma unroll
    for (int mt = 0; mt < 4; ++mt)
#pragma unroll
        for (int reg = 0; reg < 4; ++reg) {
            int m = m0 + mt * 16 + kl * 4 + reg;
            if (m < NB1) {
#pragma unroll
                for (int nt = 0; nt < 5; ++nt)
                    inp[(size_t)m * HS + w * 80 + nt * 16 + ml] = f2b(acc[mt][nt][reg]);
            }
        }
}

// ---- ygemm: y = (relu_stage ? relu(src) : src) @ WhP^T, raw bf16 ----
__global__ __launch_bounds__(256, 3) void ygemm(
    const unsigned short* __restrict__ src,  // [NB1][320] bf16
    const unsigned short* __restrict__ Wh,   // [320][320] bf16
    unsigned short* __restrict__ y,          // [NB1][320] bf16 raw
    int relu_stage)
{
    __shared__ __align__(16) short As[2][4 * 64 * 8];
    const int tid = threadIdx.x, w = tid >> 6, lane = tid & 63;
    const int ml = lane & 15, kl = lane >> 4;
    const int sr = tid & 63, seg = tid >> 6;
    const int m0 = blockIdx.x * 64;
    const int srow = (m0 + sr) < NB1 ? (m0 + sr) : SENT;
    const unsigned short* ap = src + (size_t)srow * HS + seg * 8;
    const unsigned short* bp = Wh + (size_t)(w * 80 + ml) * KP2 + kl * 8;

    f32x4 acc[4][5];
#pragma unroll
    for (int mt = 0; mt < 4; ++mt)
#pragma unroll
        for (int nt = 0; nt < 5; ++nt) acc[mt][nt] = (f32x4){0.f, 0.f, 0.f, 0.f};

    {
        uint4 av = *(const uint4*)ap;
        if (relu_stage) av = relu4(av);
        *(uint4*)&As[0][(seg * 64 + sr) * 8] = av;
    }
    uint4 Bcur[5];
#pragma unroll
    for (int nt = 0; nt < 5; ++nt) Bcur[nt] = *(const uint4*)(bp + nt * 16 * KP2);
    __syncthreads();

    for (int c = 0; c < 10; ++c) {
        uint4 an; uint4 Bn[5];
        if (c < 9) {
            an = *(const uint4*)(ap + (c + 1) * 32);
#pragma unroll
            for (int nt = 0; nt < 5; ++nt)
                Bn[nt] = *(const uint4*)(bp + (c + 1) * 32 + nt * 16 * KP2);
        }
        mfma_step(As[c & 1], Bcur, ml, kl, acc);
        if (c < 9) {
            if (relu_stage) an = relu4(an);
            *(uint4*)&As[(c + 1) & 1][(seg * 64 + sr) * 8] = an;
#pragma unroll
            for (int nt = 0; nt < 5; ++nt) Bcur[nt] = Bn[nt];
        }
        __syncthreads();
    }
#pragma unroll
    for (int mt = 0; mt < 4; ++mt)
#pragma unroll
        for (int reg = 0; reg < 4; ++reg) {
            int m = m0 + mt * 16 + kl * 4 + reg;
            if (m < NB1) {
#pragma unroll
                for (int nt = 0; nt < 5; ++nt)
                    y[(size_t)m * HS + w * 80 + nt * 16 + ml] = f2b(acc[mt][nt][reg]);
            }
        }
}

// ---- gather_bond: h' = relu(inp + sum_4 y[map]) ; 8 threads per row ----
__global__ __launch_bounds__(256) void gather_bond(
    const unsigned short* __restrict__ y, const unsigned short* __restrict__ inp,
    const int* __restrict__ mapping, unsigned short* __restrict__ hout)
{
    int t = blockIdx.x * 256 + threadIdx.x;
    int row = t >> 3, g = t & 7;
    if (row >= NB1) return;
    int4 mp = *(const int4*)(mapping + (size_t)row * 4);
    const unsigned short* r0 = y + (size_t)(mp.x < 0 ? SENT : mp.x) * HS;
    const unsigned short* r1 = y + (size_t)(mp.y < 0 ? SENT : mp.y) * HS;
    const unsigned short* r2 = y + (size_t)(mp.z < 0 ? SENT : mp.z) * HS;
    const unsigned short* r3 = y + (size_t)(mp.w < 0 ? SENT : mp.w) * HS;
    const unsigned short* ip = inp + (size_t)row * HS;
    unsigned short* op = hout + (size_t)row * HS;
#pragma unroll
    for (int s = 0; s < 5; ++s) {
        int off = (g + s * 8) * 8;
        uint4 a = *(const uint4*)(r0 + off);
        uint4 b = *(const uint4*)(r1 + off);
        uint4 c = *(const uint4*)(r2 + off);
        uint4 d = *(const uint4*)(r3 + off);
        uint4 e = *(const uint4*)(ip + off);
        uint4 o;
        {
            float lo, hi;
            lo = blo(a.x)+blo(b.x)+blo(c.x)+blo(d.x)+blo(e.x); hi = bhi(a.x)+bhi(b.x)+bhi(c.x)+bhi(d.x)+bhi(e.x);
            o.x = pk2(hi > 0.f ? hi : 0.f, lo > 0.f ? lo : 0.f);
            lo = blo(a.y)+blo(b.y)+blo(c.y)+blo(d.y)+blo(e.y); hi = bhi(a.y)+bhi(b.y)+bhi(c.y)+bhi(d.y)+bhi(e.y);
            o.y = pk2(hi > 0.f ? hi : 0.f, lo > 0.f ? lo : 0.f);
            lo = blo(a.z)+blo(b.z)+blo(c.z)+blo(d.z)+blo(e.z); hi = bhi(a.z)+bhi(b.z)+bhi(c.z)+bhi(d.z)+bhi(e.z);
            o.z = pk2(hi > 0.f ? hi : 0.f, lo > 0.f ? lo : 0.f);
            lo = blo(a.w)+blo(b.w)+blo(c.w)+blo(d.w)+blo(e.w); hi = bhi(a.w)+bhi(b.w)+bhi(c.w)+bhi(d.w)+bhi(e.w);
            o.w = pk2(hi > 0.f ? hi : 0.f, lo > 0.f ? lo : 0.f);
        }
        *(uint4*)(op + off) = o;
    }
}

// ---- gather_atom: msg = sum_4 h[a2b] (no inp, no relu) ----
__global__ __launch_bounds__(256) void gather_atom(
    const unsigned short* __restrict__ h, const int* __restrict__ a2b,
    unsigned short* __restrict__ msg)
{
    int t = blockIdx.x * 256 + threadIdx.x;
    int row = t >> 3, g = t & 7;
    int4 mp = *(const int4*)(a2b + (size_t)row * 4);
    const unsigned short* r0 = h + (size_t)(mp.x < 0 ? SENT : mp.x) * HS;
    const unsigned short* r1 = h + (size_t)(mp.y < 0 ? SENT : mp.y) * HS;
    const unsigned short* r2 = h + (size_t)(mp.z < 0 ? SENT : mp.z) * HS;
    const unsigned short* r3 = h + (size_t)(mp.w < 0 ? SENT : mp.w) * HS;
    unsigned short* op = msg + (size_t)row * HS;
#pragma unroll
    for (int s = 0; s < 5; ++s) {
        int off = (g + s * 8) * 8;
        uint4 a = *(const uint4*)(r0 + off);
        uint4 b = *(const uint4*)(r1 + off);
        uint4 c = *(const uint4*)(r2 + off);
        uint4 d = *(const uint4*)(r3 + off);
        uint4 o;
        o.x = pairsum4(a.x, b.x, c.x, d.x);
        o.y = pairsum4(a.y, b.y, c.y, d.y);
        o.z = pairsum4(a.z, b.z, c.z, d.z);
        o.w = pairsum4(a.w, b.w, c.w, d.w);
        *(uint4*)(op + off) = o;
    }
}

// ---- atom GEMM + fused molecule mean (dense A = [atomf | msg]) ----
__global__ __launch_bounds__(256, 3) void atom_gemm(
    const float* __restrict__ atomf,         // [NATOMS][133] fp32
    const unsigned short* __restrict__ msg,  // [NATOMS][320] bf16
    const unsigned short* __restrict__ WoC,  // [320][480] bf16
    const float* __restrict__ bo,            // [300]
    float* __restrict__ out)                 // [NMOLS][OUTD]
{
    __shared__ __align__(16) short As[2][4 * 64 * 8];
    const int tid = threadIdx.x, w = tid >> 6, lane = tid & 63;
    const int ml = lane & 15, kl = lane >> 4;
    const int sr = tid & 63, seg = tid >> 6;
    const int m0 = blockIdx.x * 64;
    const float* fp = atomf + (size_t)(m0 + sr) * AFD;
    const unsigned short* mp = msg + (size_t)(m0 + sr) * HS + seg * 8;
    const unsigned short* bp = WoC + (size_t)(w * 80 + ml) * KPC + kl * 8;

    f32x4 acc[4][5];
#pragma unroll
    for (int mt = 0; mt < 4; ++mt)
#pragma unroll
        for (int nt = 0; nt < 5; ++nt) acc[mt][nt] = (f32x4){0.f, 0.f, 0.f, 0.f};

    {
        union { short s[8]; uint4 u; } st;
#pragma unroll
        for (int j = 0; j < 8; ++j) {
            int k = seg * 8 + j;
            st.s[j] = (short)f2b(k < AFD ? fp[k] : 0.f);
        }
        *(uint4*)&As[0][(seg * 64 + sr) * 8] = st.u;
    }
    uint4 Bcur[5];
#pragma unroll
    for (int nt = 0; nt < 5; ++nt) Bcur[nt] = *(const uint4*)(bp + nt * 16 * KPC);
    __syncthreads();

    for (int c = 0; c < 15; ++c) {
        const int cn = c + 1;
        float vn[8]; uint4 an; uint4 Bn[5];
        if (cn < 15) {
            if (cn < 5) {
#pragma unroll
                for (int j = 0; j < 8; ++j) {
                    int k = cn * 32 + seg * 8 + j;
                    vn[j] = (k < AFD) ? fp[k] : 0.f;
                }
            } else {
                an = *(const uint4*)(mp + (cn - 5) * 32);
            }
#pragma unroll
            for (int nt = 0; nt < 5; ++nt) Bn[nt] = *(const uint4*)(bp + cn * 32 + nt * 16 * KPC);
        }
        mfma_step(As[c & 1], Bcur, ml, kl, acc);
        if (cn < 15) {
            if (cn < 5) {
                union { short s[8]; uint4 u; } st;
#pragma unroll
                for (int j = 0; j < 8; ++j) st.s[j] = (short)f2b(vn[j]);
                *(uint4*)&As[cn & 1][(seg * 64 + sr) * 8] = st.u;
            } else {
                *(uint4*)&As[cn & 1][(seg * 64 + sr) * 8] = an;
            }
#pragma unroll
            for (int nt = 0; nt < 5; ++nt) Bcur[nt] = Bn[nt];
        }
        __syncthreads();
    }

    // epilogue: bias + relu + mean over each 16-row m-tile (= 1 molecule)
#pragma unroll
    for (int mt = 0; mt < 4; ++mt) {
        int mol = blockIdx.x * 4 + mt;
#pragma unroll
        for (int nt = 0; nt < 5; ++nt) {
            int n = w * 80 + nt * 16 + ml;
            float bias = (n < DH) ? bo[n] : 0.f;
            float s = 0.f;
#pragma unroll
            for (int reg = 0; reg < 4; ++reg) {
                float v = acc[mt][nt][reg] + bias;
                s += (v > 0.f ? v : 0.f);
            }
            s += __shfl_down(s, 32, 64);
            s += __shfl_down(s, 16, 64);
            if (kl == 0 && n < DH) out[(size_t)mol * OUTD + n] = s * (1.f / 16.f);
        }
    }
}

// ===================== FALLBACK (round-5 fused, ws < 253 MB) =====================

__global__ __launch_bounds__(256, 3) void bond_gemm_fb(
    const float* __restrict__ fini, const unsigned short* __restrict__ finiB,
    const unsigned short* __restrict__ hsrc, const int* __restrict__ mapping,
    const unsigned short* __restrict__ WiP, const unsigned short* __restrict__ WhP,
    unsigned short* __restrict__ hdst, int do_msg, int useB)
{
    const int tid = threadIdx.x, wv = tid >> 6, lane = tid & 63;
    const int ml = lane & 15, kh = lane >> 4;
    const int m0 = blockIdx.x * 64 + wv * 16;
    const int mrow = m0 + ml;
    const int mrowc = mrow < NB1 ? mrow : SENT;

    f32x4 acc[20];
#pragma unroll
    for (int nt = 0; nt < 20; ++nt) acc[nt] = (f32x4){0.f, 0.f, 0.f, 0.f};

    if (useB) {
        const unsigned short* fb = finiB + (size_t)mrowc * KP1 + kh * 8;
#pragma unroll
        for (int c = 0; c < 5; ++c) {
            bf16x8 af = *(const bf16x8*)(fb + c * 32);
            const unsigned short* bp = WiP + ml * KP1 + c * 32 + kh * 8;
#pragma unroll
            for (int nt = 0; nt < 20; ++nt)
                acc[nt] = __builtin_amdgcn_mfma_f32_16x16x32_bf16(af, *(const bf16x8*)(bp + nt * 16 * KP1), acc[nt], 0, 0, 0);
        }
    } else {
        const float* fp = fini + (size_t)mrowc * CFD;
#pragma unroll
        for (int c = 0; c < 5; ++c) {
            union { short s[8]; bf16x8 x; } u;
#pragma unroll
            for (int j = 0; j < 8; ++j) {
                int k = c * 32 + kh * 8 + j;
                u.s[j] = (short)f2b(k < CFD ? fp[k] : 0.f);
            }
            const unsigned short* bp = WiP + ml * KP1 + c * 32 + kh * 8;
#pragma unroll
            for (int nt = 0; nt < 20; ++nt)
                acc[nt] = __builtin_amdgcn_mfma_f32_16x16x32_bf16(u.x, *(const bf16x8*)(bp + nt * 16 * KP1), acc[nt], 0, 0, 0);
        }
    }
    if (do_msg) {
        int4 mp = *(const int4*)(mapping + (size_t)mrowc * 4);
        const unsigned short* g0 = hsrc + (size_t)(mp.x < 0 ? SENT : mp.x) * HS + kh * 8;
        const unsigned short* g1 = hsrc + (size_t)(mp.y < 0 ? SENT : mp.y) * HS + kh * 8;
        const unsigned short* g2 = hsrc + (size_t)(mp.z < 0 ? SENT : mp.z) * HS + kh * 8;
        const unsigned short* g3 = hsrc + (size_t)(mp.w < 0 ? SENT : mp.w) * HS + kh * 8;
#pragma unroll
        for (int c = 0; c < 10; ++c) {
            uint4 a = *(const uint4*)(g0 + c * 32);
            uint4 b = *(const uint4*)(g1 + c * 32);
            uint4 cc = *(const uint4*)(g2 + c * 32);
            uint4 d = *(const uint4*)(g3 + c * 32);
            uint4 o;
            o.x = pairsum4(a.x, b.x, cc.x, d.x);
            o.y = pairsum4(a.y, b.y, cc.y, d.y);
            o.z = pairsum4(a.z, b.z, cc.z, d.z);
            o.w = pairsum4(a.w, b.w, cc.w, d.w);
            const unsigned short* bp = WhP + ml * KP2 + c * 32 + kh * 8;
#pragma unroll
            for (int nt = 0; nt < 20; ++nt)
                acc[nt] = __builtin_amdgcn_mfma_f32_16x16x32_bf16(asbf(o), *(const bf16x8*)(bp + nt * 16 * KP2), acc[nt], 0, 0, 0);
        }
    }
#pragma unroll
    for (int nt = 0; nt < 20; ++nt) {
        int n = nt * 16 + ml;
#pragma unroll
        for (int reg = 0; reg < 4; ++reg) {
            int m = m0 + kh * 4 + reg;
            if (m < NB1) {
                float v = acc[nt][reg];
                hdst[(size_t)m * HS + n] = f2b(v > 0.f ? v : 0.f);
            }
        }
    }
}

__global__ __launch_bounds__(256, 3) void atom_gemm_fb(
    const float* __restrict__ atomf, const unsigned short* __restrict__ hsrc,
    const int* __restrict__ a2b, const unsigned short* __restrict__ WoA,
    const unsigned short* __restrict__ WoB, const float* __restrict__ bo,
    float* __restrict__ out)
{
    const int tid = threadIdx.x, wv = tid >> 6, lane = tid & 63;
    const int ml = lane & 15, kh = lane >> 4;
    const int m0 = blockIdx.x * 64 + wv * 16;
    const int arow = m0 + ml;

    f32x4 acc[20];
#pragma unroll
    for (int nt = 0; nt < 20; ++nt) acc[nt] = (f32x4){0.f, 0.f, 0.f, 0.f};
    {
        const float* fp = atomf + (size_t)arow * AFD;
#pragma unroll
        for (int c = 0; c < 5; ++c) {
            union { short s[8]; bf16x8 x; } u;
#pragma unroll
            for (int j = 0; j < 8; ++j) {
                int k = c * 32 + kh * 8 + j;
                u.s[j] = (short)f2b(k < AFD ? fp[k] : 0.f);
            }
            const unsigned short* bp = WoA + ml * KP1 + c * 32 + kh * 8;
#pragma unroll
            for (int nt = 0; nt < 20; ++nt)
                acc[nt] = __builtin_amdgcn_mfma_f32_16x16x32_bf16(u.x, *(const bf16x8*)(bp + nt * 16 * KP1), acc[nt], 0, 0, 0);
        }
    }
    {
        int4 mp = *(const int4*)(a2b + (size_t)arow * 4);
        const unsigned short* g0 = hsrc + (size_t)(mp.x < 0 ? SENT : mp.x) * HS + kh * 8;
        const unsigned short* g1 = hsrc + (size_t)(mp.y < 0 ? SENT : mp.y) * HS + kh * 8;
        const unsigned short* g2 = hsrc + (size_t)(mp.z < 0 ? SENT : mp.z) * HS + kh * 8;
        const unsigned short* g3 = hsrc + (size_t)(mp.w < 0 ? SENT : mp.w) * HS + kh * 8;
#pragma unroll
        for (int c = 0; c < 10; ++c) {
            uint4 a = *(const uint4*)(g0 + c * 32);
            uint4 b = *(const uint4*)(g1 + c * 32);
            uint4 cc = *(const uint4*)(g2 + c * 32);
            uint4 d = *(const uint4*)(g3 + c * 32);
            uint4 o;
            o.x = pairsum4(a.x, b.x, cc.x, d.x);
            o.y = pairsum4(a.y, b.y, cc.y, d.y);
            o.z = pairsum4(a.z, b.z, cc.z, d.z);
            o.w = pairsum4(a.w, b.w, cc.w, d.w);
            const unsigned short* bp = WoB + ml * KP2 + c * 32 + kh * 8;
#pragma unroll
            for (int nt = 0; nt < 20; ++nt)
                acc[nt] = __builtin_amdgcn_mfma_f32_16x16x32_bf16(asbf(o), *(const bf16x8*)(bp + nt * 16 * KP2), acc[nt], 0, 0, 0);
        }
    }
    const int mol = blockIdx.x * 4 + wv;
#pragma unroll
    for (int nt = 0; nt < 20; ++nt) {
        int n = nt * 16 + ml;
        float bias = (n < DH) ? bo[n] : 0.f;
        float s = 0.f;
#pragma unroll
        for (int reg = 0; reg < 4; ++reg) {
            float v = acc[nt][reg] + bias;
            s += (v > 0.f ? v : 0.f);
        }
        s += __shfl_down(s, 32, 64);
        s += __shfl_down(s, 16, 64);
        if (kh == 0 && n < DH) out[(size_t)mol * OUTD + n] = s * (1.f / 16.f);
    }
}

__global__ void prep_fini(const float* __restrict__ fini, unsigned short* __restrict__ finiB) {
    int t = blockIdx.x * blockDim.x + threadIdx.x;
    if (t >= NB1 * 20) return;
    int row = t / 20, g = t % 20;
    const float* src = fini + (size_t)row * CFD;
    union { unsigned short s[8]; uint4 u; } o;
#pragma unroll
    for (int j = 0; j < 8; ++j) {
        int k = g * 8 + j;
        o.s[j] = (k < CFD) ? f2b(src[k]) : (unsigned short)0;
    }
    *(uint4*)(finiB + (size_t)row * KP1 + g * 8) = o.u;
}

// ===================== shared prep / copy =====================

__global__ void prep_w(const float* __restrict__ Wi, const float* __restrict__ Wh,
                       const float* __restrict__ Wo, unsigned short* __restrict__ wb, int mode) {
    int t = blockIdx.x * blockDim.x + threadIdx.x;
    if (t >= 307200) return;
    float v = 0.f;
    if (t < 51200) {                       // WiP [320][160]
        int n = t / 160, k = t % 160;
        if (n < DH && k < CFD) v = Wi[n * CFD + k];
    } else if (t < 153600) {               // WhP [320][320]
        int q = t - 51200; int n = q / 320, k = q % 320;
        if (n < DH && k < DH) v = Wh[n * DH + k];
    } else if (mode) {                     // WoC [320][480]
        int q = t - 153600; int n = q / 480, k = q % 480;
        if (n < DH) {
            if (k < AFD) v = Wo[n * 433 + k];
            else if (k >= 160 && k < 460) v = Wo[n * 433 + AFD + (k - 160)];
        }
    } else if (t < 204800) {               // WoA [320][160]
        int q = t - 153600; int n = q / 160, k = q % 160;
        if (n < DH && k < AFD) v = Wo[n * 433 + k];
    } else {                               // WoB [320][320]
        int q = t - 204800; int n = q / 320, k = q % 320;
        if (n < DH && k < DH) v = Wo[n * 433 + AFD + k];
    }
    wb[t] = f2b(v);
}

__global__ void copy_gf(const float4* __restrict__ gf, float* __restrict__ out) {
    int t = blockIdx.x * blockDim.x + threadIdx.x;
    if (t >= NMOLS * (GFD / 4)) return;
    int mol = t >> 9;
    int g4 = t & 511;
    float4 v = gf[t];
    *(float4*)(out + (size_t)mol * OUTD + DH + g4 * 4) = v;
}

extern "C" void kernel_launch(void* const* d_in, const int* in_sizes, int n_in,
                              void* d_out, int out_size, void* d_ws, size_t ws_size,
                              hipStream_t stream) {
    const float* atomf   = (const float*)d_in[0];
    const float* fini    = (const float*)d_in[1];
    const int*   a2b     = (const int*)d_in[2];
    const int*   mapping = (const int*)d_in[3];
    const float* gf      = (const float*)d_in[4];
    const float* W_i     = (const float*)d_in[5];
    const float* W_h     = (const float*)d_in[6];
    const float* W_o     = (const float*)d_in[7];
    const float* b_o     = (const float*)d_in[8];
    float* out = (float*)d_out;

    char* ws = (char*)d_ws;
    size_t SA = (((size_t)NB1 * HS * 2) + 255) & ~(size_t)255;  // 83.89 MB
    size_t SW = 307200 * 2;
    dim3 blk(256);

    if (ws_size >= 3 * SA + SW) {
        // primary: inp | bufA | bufB | weights ; msg aliases inp (dead by then)
        unsigned short* inp  = (unsigned short*)ws;
        unsigned short* bufA = (unsigned short*)(ws + SA);
        unsigned short* bufB = (unsigned short*)(ws + 2 * SA);
        unsigned short* wb   = (unsigned short*)(ws + 3 * SA);
        unsigned short* WiP = wb;
        unsigned short* WhP = wb + 51200;
        unsigned short* WoC = wb + 153600;
        unsigned short* msg = inp;

        prep_w<<<1200, blk, 0, stream>>>(W_i, W_h, W_o, wb, 1);
        gemm1<<<2049, blk, 0, stream>>>(fini, WiP, inp);
        ygemm<<<2049, blk, 0, stream>>>(inp, WhP, bufB, 1);          // y1 = relu(inp)@Wh
        gather_bond<<<4097, blk, 0, stream>>>(bufB, inp, mapping, bufA);  // h1
        ygemm<<<2049, blk, 0, stream>>>(bufA, WhP, bufB, 0);         // y2 = h1@Wh
        gather_bond<<<4097, blk, 0, stream>>>(bufB, inp, mapping, bufA);  // h2
        gather_atom<<<2048, blk, 0, stream>>>(bufA, a2b, msg);
        atom_gemm<<<1024, blk, 0, stream>>>(atomf, msg, WoC, b_o, out);
    } else {
        // fallback: round-5 fused path (h_a | h_b | weights [| finiB])
        size_t SF = (size_t)NB1 * KP1 * 2;
        unsigned short* h_a = (unsigned short*)ws;
        unsigned short* h_b = (unsigned short*)(ws + SA);
        unsigned short* wb  = (unsigned short*)(ws + 2 * SA);
        unsigned short* finiB = (unsigned short*)(ws + 2 * SA + SW);
        unsigned short* WiP = wb;
        unsigned short* WhP = wb + 51200;
        unsigned short* WoA = wb + 153600;
        unsigned short* WoB = wb + 204800;
        int useB = (ws_size >= 2 * SA + SW + SF) ? 1 : 0;

        prep_w<<<1200, blk, 0, stream>>>(W_i, W_h, W_o, wb, 0);
        if (useB) prep_fini<<<(NB1 * 20 + 255) / 256, blk, 0, stream>>>(fini, finiB);
        bond_gemm_fb<<<2049, blk, 0, stream>>>(fini, finiB, h_a, mapping, WiP, WhP, h_a, 0, useB);
        bond_gemm_fb<<<2049, blk, 0, stream>>>(fini, finiB, h_a, mapping, WiP, WhP, h_b, 1, useB);
        bond_gemm_fb<<<2049, blk, 0, stream>>>(fini, finiB, h_b, mapping, WiP, WhP, h_a, 1, useB);
        atom_gemm_fb<<<1024, blk, 0, stream>>>(atomf, h_a, a2b, WoA, WoB, b_o, out);
    }
    copy_gf<<<NMOLS * (GFD / 4) / 256, blk, 0, stream>>>((const float4*)gf, out);
}

// Round 7
// 584.317 us; speedup vs baseline: 1.9022x; 1.0483x over previous
//
#include <hip/hip_runtime.h>

typedef short bf16x8 __attribute__((ext_vector_type(8)));
typedef float f32x4 __attribute__((ext_vector_type(4)));

constexpr int NB1    = 131073;   // num_bonds + 1 (row 131072 = zero sentinel)
constexpr int SENT   = 131072;
constexpr int NATOMS = 65536;
constexpr int AFD    = 133;
constexpr int CFD    = 147;
constexpr int DH     = 300;
constexpr int GFD    = 2048;
constexpr int NMOLS  = 4096;
constexpr int OUTD   = DH + GFD; // 2348
constexpr int HS     = 320;      // h/y/inp row stride (bf16) = padded N
constexpr int KP1    = 160;      // padded CFD / AFD
constexpr int KP2    = 320;      // padded DH
constexpr int KPC    = 480;      // padded concat K for atom GEMM
constexpr int LSTR   = 328;      // LDS A-tile row stride (320 + 8 pad)
constexpr int LSTRC  = 488;      // LDS A-tile row stride for atom (480 + 8)

__device__ __forceinline__ unsigned short f2b(float f) {
    unsigned u = __float_as_uint(f);
    u += 0x7fffu + ((u >> 16) & 1u);
    return (unsigned short)(u >> 16);
}
__device__ __forceinline__ float blo(unsigned x) { return __uint_as_float(x << 16); }
__device__ __forceinline__ float bhi(unsigned x) { return __uint_as_float(x & 0xffff0000u); }
__device__ __forceinline__ unsigned pk2(float hi, float lo) {
    return ((unsigned)f2b(hi) << 16) | (unsigned)f2b(lo);
}
__device__ __forceinline__ unsigned pairsum4(unsigned a, unsigned b, unsigned c, unsigned d) {
    float lo = blo(a) + blo(b) + blo(c) + blo(d);
    float hi = bhi(a) + bhi(b) + bhi(c) + bhi(d);
    return pk2(hi, lo);
}
__device__ __forceinline__ bf16x8 asbf(uint4 u) {
    union { uint4 u; bf16x8 b; } c; c.u = u; return c.b;
}

// ===================== PRIMARY PATH =====================

// ---- K1: inp = fini @ Wi^T (write raw); y1 = relu(inp) @ Wh^T (write raw) ----
__global__ __launch_bounds__(256, 2) void fused_in(
    const float* __restrict__ fini,          // [NB1][147] fp32
    const unsigned short* __restrict__ WiP,  // [320][160] bf16
    const unsigned short* __restrict__ WhP,  // [320][320] bf16
    unsigned short* __restrict__ inp,        // [NB1][320] bf16 raw
    unsigned short* __restrict__ y1)         // [NB1][320] bf16 raw
{
    __shared__ __align__(16) short As[64 * LSTR];  // 41 KB
    const int tid = threadIdx.x, w = tid >> 6, lane = tid & 63;
    const int ml = lane & 15, kl = lane >> 4;
    const int m0 = blockIdx.x * 64;

    f32x4 acc[4][5];
#pragma unroll
    for (int mt = 0; mt < 4; ++mt)
#pragma unroll
        for (int nt = 0; nt < 5; ++nt) acc[mt][nt] = (f32x4){0.f, 0.f, 0.f, 0.f};

    // ---- phase 1: fragment-direct A from fini fp32, K=160, no barriers ----
    const float* fr[4];
#pragma unroll
    for (int mt = 0; mt < 4; ++mt) {
        int r = m0 + mt * 16 + ml;
        fr[mt] = fini + (size_t)(r < NB1 ? r : SENT) * CFD + kl * 8;
    }
    const unsigned short* bpi = WiP + (size_t)(w * 80 + ml) * KP1 + kl * 8;
#pragma unroll
    for (int c = 0; c < 5; ++c) {
        uint4 B[5];
#pragma unroll
        for (int nt = 0; nt < 5; ++nt) B[nt] = *(const uint4*)(bpi + c * 32 + nt * 16 * KP1);
        bf16x8 af[4];
#pragma unroll
        for (int mt = 0; mt < 4; ++mt) {
            union { short s[8]; bf16x8 x; } u;
            if (c < 4) {
#pragma unroll
                for (int j = 0; j < 8; ++j) u.s[j] = (short)f2b(fr[mt][c * 32 + j]);
            } else {
#pragma unroll
                for (int j = 0; j < 8; ++j) {
                    int k = 128 + kl * 8 + j;
                    u.s[j] = (short)f2b(k < CFD ? fr[mt][c * 32 + j] : 0.f);
                }
            }
            af[mt] = u.x;
        }
#pragma unroll
        for (int mt = 0; mt < 4; ++mt)
#pragma unroll
            for (int nt = 0; nt < 5; ++nt)
                acc[mt][nt] = __builtin_amdgcn_mfma_f32_16x16x32_bf16(af[mt], asbf(B[nt]), acc[mt][nt], 0, 0, 0);
    }

    // ---- epilogue 1: write inp (raw) + stage relu(inp) tile into LDS ----
#pragma unroll
    for (int mt = 0; mt < 4; ++mt)
#pragma unroll
        for (int reg = 0; reg < 4; ++reg) {
            int lr = mt * 16 + kl * 4 + reg;
            int m = m0 + lr;
#pragma unroll
            for (int nt = 0; nt < 5; ++nt) {
                int col = w * 80 + nt * 16 + ml;
                float v = acc[mt][nt][reg];
                if (m < NB1) inp[(size_t)m * HS + col] = f2b(v);
                As[lr * LSTR + col] = (short)f2b(v > 0.f ? v : 0.f);
            }
        }
    __syncthreads();   // the ONLY barrier

    // ---- phase 2: y1 = LDS-tile @ Wh^T, K=320, barrier-free chunks ----
#pragma unroll
    for (int mt = 0; mt < 4; ++mt)
#pragma unroll
        for (int nt = 0; nt < 5; ++nt) acc[mt][nt] = (f32x4){0.f, 0.f, 0.f, 0.f};
    const unsigned short* bph = WhP + (size_t)(w * 80 + ml) * KP2 + kl * 8;
#pragma unroll
    for (int c = 0; c < 10; ++c) {
        uint4 B[5];
#pragma unroll
        for (int nt = 0; nt < 5; ++nt) B[nt] = *(const uint4*)(bph + c * 32 + nt * 16 * KP2);
        bf16x8 af[4];
#pragma unroll
        for (int mt = 0; mt < 4; ++mt)
            af[mt] = *(const bf16x8*)&As[(mt * 16 + ml) * LSTR + c * 32 + kl * 8];
#pragma unroll
        for (int mt = 0; mt < 4; ++mt)
#pragma unroll
            for (int nt = 0; nt < 5; ++nt)
                acc[mt][nt] = __builtin_amdgcn_mfma_f32_16x16x32_bf16(af[mt], asbf(B[nt]), acc[mt][nt], 0, 0, 0);
    }
#pragma unroll
    for (int mt = 0; mt < 4; ++mt)
#pragma unroll
        for (int reg = 0; reg < 4; ++reg) {
            int m = m0 + mt * 16 + kl * 4 + reg;
            if (m < NB1) {
#pragma unroll
                for (int nt = 0; nt < 5; ++nt)
                    y1[(size_t)m * HS + w * 80 + nt * 16 + ml] = f2b(acc[mt][nt][reg]);
            }
        }
}

// ---- K2: ydst = relu(inp + sum_4 ysrc[map]) @ Wh^T  (h-tile staged in LDS, never stored) ----
__global__ __launch_bounds__(256, 2) void fused_mid(
    const unsigned short* __restrict__ ysrc,
    const unsigned short* __restrict__ inp,
    const int* __restrict__ mapping,
    const unsigned short* __restrict__ WhP,
    unsigned short* __restrict__ ydst)
{
    __shared__ __align__(16) short As[64 * LSTR];
    const int tid = threadIdx.x, w = tid >> 6, lane = tid & 63;
    const int ml = lane & 15, kl = lane >> 4;
    const int m0 = blockIdx.x * 64;

    // ---- stage h-tile: 4 threads/row, 10 uint4-segments each, all loads upfront ----
    {
        const int sr = tid & 63, sg = tid >> 6;
        int srow = m0 + sr;
        int crow = srow < NB1 ? srow : SENT;
        int4 mp = *(const int4*)(mapping + (size_t)crow * 4);
        const unsigned short* r0 = ysrc + (size_t)(mp.x < 0 ? SENT : mp.x) * HS;
        const unsigned short* r1 = ysrc + (size_t)(mp.y < 0 ? SENT : mp.y) * HS;
        const unsigned short* r2 = ysrc + (size_t)(mp.z < 0 ? SENT : mp.z) * HS;
        const unsigned short* r3 = ysrc + (size_t)(mp.w < 0 ? SENT : mp.w) * HS;
        const unsigned short* ip = inp + (size_t)crow * HS;
#pragma unroll
        for (int s = 0; s < 10; ++s) {
            int off = (s * 4 + sg) * 8;
            uint4 a = *(const uint4*)(r0 + off);
            uint4 b = *(const uint4*)(r1 + off);
            uint4 c = *(const uint4*)(r2 + off);
            uint4 d = *(const uint4*)(r3 + off);
            uint4 e = *(const uint4*)(ip + off);
            uint4 o;
            float lo, hi;
            lo = blo(a.x)+blo(b.x)+blo(c.x)+blo(d.x)+blo(e.x); hi = bhi(a.x)+bhi(b.x)+bhi(c.x)+bhi(d.x)+bhi(e.x);
            o.x = pk2(hi > 0.f ? hi : 0.f, lo > 0.f ? lo : 0.f);
            lo = blo(a.y)+blo(b.y)+blo(c.y)+blo(d.y)+blo(e.y); hi = bhi(a.y)+bhi(b.y)+bhi(c.y)+bhi(d.y)+bhi(e.y);
            o.y = pk2(hi > 0.f ? hi : 0.f, lo > 0.f ? lo : 0.f);
            lo = blo(a.z)+blo(b.z)+blo(c.z)+blo(d.z)+blo(e.z); hi = bhi(a.z)+bhi(b.z)+bhi(c.z)+bhi(d.z)+bhi(e.z);
            o.z = pk2(hi > 0.f ? hi : 0.f, lo > 0.f ? lo : 0.f);
            lo = blo(a.w)+blo(b.w)+blo(c.w)+blo(d.w)+blo(e.w); hi = bhi(a.w)+bhi(b.w)+bhi(c.w)+bhi(d.w)+bhi(e.w);
            o.w = pk2(hi > 0.f ? hi : 0.f, lo > 0.f ? lo : 0.f);
            *(uint4*)&As[sr * LSTR + off] = o;
        }
    }
    __syncthreads();   // the ONLY barrier

    f32x4 acc[4][5];
#pragma unroll
    for (int mt = 0; mt < 4; ++mt)
#pragma unroll
        for (int nt = 0; nt < 5; ++nt) acc[mt][nt] = (f32x4){0.f, 0.f, 0.f, 0.f};
    const unsigned short* bph = WhP + (size_t)(w * 80 + ml) * KP2 + kl * 8;
#pragma unroll
    for (int c = 0; c < 10; ++c) {
        uint4 B[5];
#pragma unroll
        for (int nt = 0; nt < 5; ++nt) B[nt] = *(const uint4*)(bph + c * 32 + nt * 16 * KP2);
        bf16x8 af[4];
#pragma unroll
        for (int mt = 0; mt < 4; ++mt)
            af[mt] = *(const bf16x8*)&As[(mt * 16 + ml) * LSTR + c * 32 + kl * 8];
#pragma unroll
        for (int mt = 0; mt < 4; ++mt)
#pragma unroll
            for (int nt = 0; nt < 5; ++nt)
                acc[mt][nt] = __builtin_amdgcn_mfma_f32_16x16x32_bf16(af[mt], asbf(B[nt]), acc[mt][nt], 0, 0, 0);
    }
#pragma unroll
    for (int mt = 0; mt < 4; ++mt)
#pragma unroll
        for (int reg = 0; reg < 4; ++reg) {
            int m = m0 + mt * 16 + kl * 4 + reg;
            if (m < NB1) {
#pragma unroll
                for (int nt = 0; nt < 5; ++nt)
                    ydst[(size_t)m * HS + w * 80 + nt * 16 + ml] = f2b(acc[mt][nt][reg]);
            }
        }
}

// ---- K3: h2 = relu(inp + sum_4 y2[map]) (materialized for the atom gather) ----
__global__ __launch_bounds__(256) void gather_bond(
    const unsigned short* __restrict__ y, const unsigned short* __restrict__ inp,
    const int* __restrict__ mapping, unsigned short* __restrict__ hout)
{
    int t = blockIdx.x * 256 + threadIdx.x;
    int row = t >> 3, g = t & 7;
    if (row >= NB1) return;
    int4 mp = *(const int4*)(mapping + (size_t)row * 4);
    const unsigned short* r0 = y + (size_t)(mp.x < 0 ? SENT : mp.x) * HS;
    const unsigned short* r1 = y + (size_t)(mp.y < 0 ? SENT : mp.y) * HS;
    const unsigned short* r2 = y + (size_t)(mp.z < 0 ? SENT : mp.z) * HS;
    const unsigned short* r3 = y + (size_t)(mp.w < 0 ? SENT : mp.w) * HS;
    const unsigned short* ip = inp + (size_t)row * HS;
    unsigned short* op = hout + (size_t)row * HS;
#pragma unroll
    for (int s = 0; s < 5; ++s) {
        int off = (g + s * 8) * 8;
        uint4 a = *(const uint4*)(r0 + off);
        uint4 b = *(const uint4*)(r1 + off);
        uint4 c = *(const uint4*)(r2 + off);
        uint4 d = *(const uint4*)(r3 + off);
        uint4 e = *(const uint4*)(ip + off);
        uint4 o;
        float lo, hi;
        lo = blo(a.x)+blo(b.x)+blo(c.x)+blo(d.x)+blo(e.x); hi = bhi(a.x)+bhi(b.x)+bhi(c.x)+bhi(d.x)+bhi(e.x);
        o.x = pk2(hi > 0.f ? hi : 0.f, lo > 0.f ? lo : 0.f);
        lo = blo(a.y)+blo(b.y)+blo(c.y)+blo(d.y)+blo(e.y); hi = bhi(a.y)+bhi(b.y)+bhi(c.y)+bhi(d.y)+bhi(e.y);
        o.y = pk2(hi > 0.f ? hi : 0.f, lo > 0.f ? lo : 0.f);
        lo = blo(a.z)+blo(b.z)+blo(c.z)+blo(d.z)+blo(e.z); hi = bhi(a.z)+bhi(b.z)+bhi(c.z)+bhi(d.z)+bhi(e.z);
        o.z = pk2(hi > 0.f ? hi : 0.f, lo > 0.f ? lo : 0.f);
        lo = blo(a.w)+blo(b.w)+blo(c.w)+blo(d.w)+blo(e.w); hi = bhi(a.w)+bhi(b.w)+bhi(c.w)+bhi(d.w)+bhi(e.w);
        o.w = pk2(hi > 0.f ? hi : 0.f, lo > 0.f ? lo : 0.f);
        *(uint4*)(op + off) = o;
    }
}

// ---- K4: out[mol][0:300] = mean_16 relu([atomf | sum_4 h[a2b]] @ WoC^T + bo) ----
__global__ __launch_bounds__(256, 2) void fused_atom(
    const float* __restrict__ atomf,         // [NATOMS][133] fp32
    const unsigned short* __restrict__ h,    // [NB1][320] bf16
    const int* __restrict__ a2b,             // [NATOMS][4]
    const unsigned short* __restrict__ WoC,  // [320][480] bf16
    const float* __restrict__ bo,            // [300]
    float* __restrict__ out)                 // [NMOLS][OUTD]
{
    __shared__ __align__(16) short As[64 * LSTRC];  // 61 KB
    const int tid = threadIdx.x, w = tid >> 6, lane = tid & 63;
    const int ml = lane & 15, kl = lane >> 4;
    const int m0 = blockIdx.x * 64;

    // ---- stage [atomf | gather-sum h] tile: 4 threads/row, 15 segments each ----
    {
        const int sr = tid & 63, sg = tid >> 6;
        int row = m0 + sr;
        int4 mp = *(const int4*)(a2b + (size_t)row * 4);
        const unsigned short* r0 = h + (size_t)(mp.x < 0 ? SENT : mp.x) * HS;
        const unsigned short* r1 = h + (size_t)(mp.y < 0 ? SENT : mp.y) * HS;
        const unsigned short* r2 = h + (size_t)(mp.z < 0 ? SENT : mp.z) * HS;
        const unsigned short* r3 = h + (size_t)(mp.w < 0 ? SENT : mp.w) * HS;
        const float* fp = atomf + (size_t)row * AFD;
#pragma unroll
        for (int s = 0; s < 15; ++s) {
            int k0 = (s * 4 + sg) * 8;
            if (k0 < KP1) {
                union { short s8[8]; uint4 u; } u;
#pragma unroll
                for (int j = 0; j < 8; ++j) {
                    int k = k0 + j;
                    u.s8[j] = (short)f2b(k < AFD ? fp[k] : 0.f);
                }
                *(uint4*)&As[sr * LSTRC + k0] = u.u;
            } else {
                int off = k0 - KP1;
                uint4 a = *(const uint4*)(r0 + off);
                uint4 b = *(const uint4*)(r1 + off);
                uint4 c = *(const uint4*)(r2 + off);
                uint4 d = *(const uint4*)(r3 + off);
                uint4 o;
                o.x = pairsum4(a.x, b.x, c.x, d.x);
                o.y = pairsum4(a.y, b.y, c.y, d.y);
                o.z = pairsum4(a.z, b.z, c.z, d.z);
                o.w = pairsum4(a.w, b.w, c.w, d.w);
                *(uint4*)&As[sr * LSTRC + k0] = o;
            }
        }
    }
    __syncthreads();   // the ONLY barrier

    f32x4 acc[4][5];
#pragma unroll
    for (int mt = 0; mt < 4; ++mt)
#pragma unroll
        for (int nt = 0; nt < 5; ++nt) acc[mt][nt] = (f32x4){0.f, 0.f, 0.f, 0.f};
    const unsigned short* bp = WoC + (size_t)(w * 80 + ml) * KPC + kl * 8;
#pragma unroll
    for (int c = 0; c < 15; ++c) {
        uint4 B[5];
#pragma unroll
        for (int nt = 0; nt < 5; ++nt) B[nt] = *(const uint4*)(bp + c * 32 + nt * 16 * KPC);
        bf16x8 af[4];
#pragma unroll
        for (int mt = 0; mt < 4; ++mt)
            af[mt] = *(const bf16x8*)&As[(mt * 16 + ml) * LSTRC + c * 32 + kl * 8];
#pragma unroll
        for (int mt = 0; mt < 4; ++mt)
#pragma unroll
            for (int nt = 0; nt < 5; ++nt)
                acc[mt][nt] = __builtin_amdgcn_mfma_f32_16x16x32_bf16(af[mt], asbf(B[nt]), acc[mt][nt], 0, 0, 0);
    }

    // ---- epilogue: bias + relu + mean over each 16-row m-tile (= 1 molecule) ----
#pragma unroll
    for (int mt = 0; mt < 4; ++mt) {
        int mol = blockIdx.x * 4 + mt;
#pragma unroll
        for (int nt = 0; nt < 5; ++nt) {
            int n = w * 80 + nt * 16 + ml;
            float bias = (n < DH) ? bo[n] : 0.f;
            float s = 0.f;
#pragma unroll
            for (int reg = 0; reg < 4; ++reg) {
                float v = acc[mt][nt][reg] + bias;
                s += (v > 0.f ? v : 0.f);
            }
            s += __shfl_down(s, 32, 64);
            s += __shfl_down(s, 16, 64);
            if (kl == 0 && n < DH) out[(size_t)mol * OUTD + n] = s * (1.f / 16.f);
        }
    }
}

// ===================== FALLBACK (round-5 fused, ws < 252 MB) =====================

__global__ __launch_bounds__(256, 3) void bond_gemm_fb(
    const float* __restrict__ fini, const unsigned short* __restrict__ hsrc,
    const int* __restrict__ mapping, const unsigned short* __restrict__ WiP,
    const unsigned short* __restrict__ WhP, unsigned short* __restrict__ hdst,
    int do_msg)
{
    const int tid = threadIdx.x, wv = tid >> 6, lane = tid & 63;
    const int ml = lane & 15, kh = lane >> 4;
    const int m0 = blockIdx.x * 64 + wv * 16;
    const int mrow = m0 + ml;
    const int mrowc = mrow < NB1 ? mrow : SENT;

    f32x4 acc[20];
#pragma unroll
    for (int nt = 0; nt < 20; ++nt) acc[nt] = (f32x4){0.f, 0.f, 0.f, 0.f};
    {
        const float* fp = fini + (size_t)mrowc * CFD;
#pragma unroll
        for (int c = 0; c < 5; ++c) {
            union { short s[8]; bf16x8 x; } u;
#pragma unroll
            for (int j = 0; j < 8; ++j) {
                int k = c * 32 + kh * 8 + j;
                u.s[j] = (short)f2b(k < CFD ? fp[k] : 0.f);
            }
            const unsigned short* bp = WiP + ml * KP1 + c * 32 + kh * 8;
#pragma unroll
            for (int nt = 0; nt < 20; ++nt)
                acc[nt] = __builtin_amdgcn_mfma_f32_16x16x32_bf16(u.x, *(const bf16x8*)(bp + nt * 16 * KP1), acc[nt], 0, 0, 0);
        }
    }
    if (do_msg) {
        int4 mp = *(const int4*)(mapping + (size_t)mrowc * 4);
        const unsigned short* g0 = hsrc + (size_t)(mp.x < 0 ? SENT : mp.x) * HS + kh * 8;
        const unsigned short* g1 = hsrc + (size_t)(mp.y < 0 ? SENT : mp.y) * HS + kh * 8;
        const unsigned short* g2 = hsrc + (size_t)(mp.z < 0 ? SENT : mp.z) * HS + kh * 8;
        const unsigned short* g3 = hsrc + (size_t)(mp.w < 0 ? SENT : mp.w) * HS + kh * 8;
#pragma unroll
        for (int c = 0; c < 10; ++c) {
            uint4 a = *(const uint4*)(g0 + c * 32);
            uint4 b = *(const uint4*)(g1 + c * 32);
            uint4 cc = *(const uint4*)(g2 + c * 32);
            uint4 d = *(const uint4*)(g3 + c * 32);
            uint4 o;
            o.x = pairsum4(a.x, b.x, cc.x, d.x);
            o.y = pairsum4(a.y, b.y, cc.y, d.y);
            o.z = pairsum4(a.z, b.z, cc.z, d.z);
            o.w = pairsum4(a.w, b.w, cc.w, d.w);
            const unsigned short* bp = WhP + ml * KP2 + c * 32 + kh * 8;
#pragma unroll
            for (int nt = 0; nt < 20; ++nt)
                acc[nt] = __builtin_amdgcn_mfma_f32_16x16x32_bf16(asbf(o), *(const bf16x8*)(bp + nt * 16 * KP2), acc[nt], 0, 0, 0);
        }
    }
#pragma unroll
    for (int nt = 0; nt < 20; ++nt) {
        int n = nt * 16 + ml;
#pragma unroll
        for (int reg = 0; reg < 4; ++reg) {
            int m = m0 + kh * 4 + reg;
            if (m < NB1) {
                float v = acc[nt][reg];
                hdst[(size_t)m * HS + n] = f2b(v > 0.f ? v : 0.f);
            }
        }
    }
}

__global__ __launch_bounds__(256, 3) void atom_gemm_fb(
    const float* __restrict__ atomf, const unsigned short* __restrict__ hsrc,
    const int* __restrict__ a2b, const unsigned short* __restrict__ WoA,
    const unsigned short* __restrict__ WoB, const float* __restrict__ bo,
    float* __restrict__ out)
{
    const int tid = threadIdx.x, wv = tid >> 6, lane = tid & 63;
    const int ml = lane & 15, kh = lane >> 4;
    const int m0 = blockIdx.x * 64 + wv * 16;
    const int arow = m0 + ml;

    f32x4 acc[20];
#pragma unroll
    for (int nt = 0; nt < 20; ++nt) acc[nt] = (f32x4){0.f, 0.f, 0.f, 0.f};
    {
        const float* fp = atomf + (size_t)arow * AFD;
#pragma unroll
        for (int c = 0; c < 5; ++c) {
            union { short s[8]; bf16x8 x; } u;
#pragma unroll
            for (int j = 0; j < 8; ++j) {
                int k = c * 32 + kh * 8 + j;
                u.s[j] = (short)f2b(k < AFD ? fp[k] : 0.f);
            }
            const unsigned short* bp = WoA + ml * KP1 + c * 32 + kh * 8;
#pragma unroll
            for (int nt = 0; nt < 20; ++nt)
                acc[nt] = __builtin_amdgcn_mfma_f32_16x16x32_bf16(u.x, *(const bf16x8*)(bp + nt * 16 * KP1), acc[nt], 0, 0, 0);
        }
    }
    {
        int4 mp = *(const int4*)(a2b + (size_t)arow * 4);
        const unsigned short* g0 = hsrc + (size_t)(mp.x < 0 ? SENT : mp.x) * HS + kh * 8;
        const unsigned short* g1 = hsrc + (size_t)(mp.y < 0 ? SENT : mp.y) * HS + kh * 8;
        const unsigned short* g2 = hsrc + (size_t)(mp.z < 0 ? SENT : mp.z) * HS + kh * 8;
        const unsigned short* g3 = hsrc + (size_t)(mp.w < 0 ? SENT : mp.w) * HS + kh * 8;
#pragma unroll
        for (int c = 0; c < 10; ++c) {
            uint4 a = *(const uint4*)(g0 + c * 32);
            uint4 b = *(const uint4*)(g1 + c * 32);
            uint4 cc = *(const uint4*)(g2 + c * 32);
            uint4 d = *(const uint4*)(g3 + c * 32);
            uint4 o;
            o.x = pairsum4(a.x, b.x, cc.x, d.x);
            o.y = pairsum4(a.y, b.y, cc.y, d.y);
            o.z = pairsum4(a.z, b.z, cc.z, d.z);
            o.w = pairsum4(a.w, b.w, cc.w, d.w);
            const unsigned short* bp = WoB + ml * KP2 + c * 32 + kh * 8;
#pragma unroll
            for (int nt = 0; nt < 20; ++nt)
                acc[nt] = __builtin_amdgcn_mfma_f32_16x16x32_bf16(asbf(o), *(const bf16x8*)(bp + nt * 16 * KP2), acc[nt], 0, 0, 0);
        }
    }
    const int mol = blockIdx.x * 4 + wv;
#pragma unroll
    for (int nt = 0; nt < 20; ++nt) {
        int n = nt * 16 + ml;
        float bias = (n < DH) ? bo[n] : 0.f;
        float s = 0.f;
#pragma unroll
        for (int reg = 0; reg < 4; ++reg) {
            float v = acc[nt][reg] + bias;
            s += (v > 0.f ? v : 0.f);
        }
        s += __shfl_down(s, 32, 64);
        s += __shfl_down(s, 16, 64);
        if (kh == 0 && n < DH) out[(size_t)mol * OUTD + n] = s * (1.f / 16.f);
    }
}

// ===================== shared prep / copy =====================

__global__ void prep_w(const float* __restrict__ Wi, const float* __restrict__ Wh,
                       const float* __restrict__ Wo, unsigned short* __restrict__ wb, int mode) {
    int t = blockIdx.x * blockDim.x + threadIdx.x;
    if (t >= 307200) return;
    float v = 0.f;
    if (t < 51200) {                       // WiP [320][160]
        int n = t / 160, k = t % 160;
        if (n < DH && k < CFD) v = Wi[n * CFD + k];
    } else if (t < 153600) {               // WhP [320][320]
        int q = t - 51200; int n = q / 320, k = q % 320;
        if (n < DH && k < DH) v = Wh[n * DH + k];
    } else if (mode) {                     // WoC [320][480]
        int q = t - 153600; int n = q / 480, k = q % 480;
        if (n < DH) {
            if (k < AFD) v = Wo[n * 433 + k];
            else if (k >= 160 && k < 460) v = Wo[n * 433 + AFD + (k - 160)];
        }
    } else if (t < 204800) {               // WoA [320][160]
        int q = t - 153600; int n = q / 160, k = q % 160;
        if (n < DH && k < AFD) v = Wo[n * 433 + k];
    } else {                               // WoB [320][320]
        int q = t - 204800; int n = q / 320, k = q % 320;
        if (n < DH && k < DH) v = Wo[n * 433 + AFD + k];
    }
    wb[t] = f2b(v);
}

__global__ void copy_gf(const float4* __restrict__ gf, float* __restrict__ out) {
    int t = blockIdx.x * blockDim.x + threadIdx.x;
    if (t >= NMOLS * (GFD / 4)) return;
    int mol = t >> 9;
    int g4 = t & 511;
    float4 v = gf[t];
    *(float4*)(out + (size_t)mol * OUTD + DH + g4 * 4) = v;
}

extern "C" void kernel_launch(void* const* d_in, const int* in_sizes, int n_in,
                              void* d_out, int out_size, void* d_ws, size_t ws_size,
                              hipStream_t stream) {
    const float* atomf   = (const float*)d_in[0];
    const float* fini    = (const float*)d_in[1];
    const int*   a2b     = (const int*)d_in[2];
    const int*   mapping = (const int*)d_in[3];
    const float* gf      = (const float*)d_in[4];
    const float* W_i     = (const float*)d_in[5];
    const float* W_h     = (const float*)d_in[6];
    const float* W_o     = (const float*)d_in[7];
    const float* b_o     = (const float*)d_in[8];
    float* out = (float*)d_out;

    char* ws = (char*)d_ws;
    size_t SA = (((size_t)NB1 * HS * 2) + 255) & ~(size_t)255;  // 83.89 MB
    size_t SW = 307200 * 2;
    dim3 blk(256);

    if (ws_size >= 3 * SA + SW) {
        // primary: inp | y1 | y2 | weights ; h2 aliases y1 (dead after K2)
        unsigned short* inp = (unsigned short*)ws;
        unsigned short* y1  = (unsigned short*)(ws + SA);
        unsigned short* y2  = (unsigned short*)(ws + 2 * SA);
        unsigned short* wb  = (unsigned short*)(ws + 3 * SA);
        unsigned short* WiP = wb;
        unsigned short* WhP = wb + 51200;
        unsigned short* WoC = wb + 153600;
        unsigned short* h2  = y1;

        prep_w<<<1200, blk, 0, stream>>>(W_i, W_h, W_o, wb, 1);
        fused_in<<<2049, blk, 0, stream>>>(fini, WiP, WhP, inp, y1);
        fused_mid<<<2049, blk, 0, stream>>>(y1, inp, mapping, WhP, y2);
        gather_bond<<<4097, blk, 0, stream>>>(y2, inp, mapping, h2);
        fused_atom<<<1024, blk, 0, stream>>>(atomf, h2, a2b, WoC, b_o, out);
    } else {
        // fallback: round-5 fused path (h_a | h_b | weights)
        unsigned short* h_a = (unsigned short*)ws;
        unsigned short* h_b = (unsigned short*)(ws + SA);
        unsigned short* wb  = (unsigned short*)(ws + 2 * SA);
        unsigned short* WiP = wb;
        unsigned short* WhP = wb + 51200;
        unsigned short* WoA = wb + 153600;
        unsigned short* WoB = wb + 204800;

        prep_w<<<1200, blk, 0, stream>>>(W_i, W_h, W_o, wb, 0);
        bond_gemm_fb<<<2049, blk, 0, stream>>>(fini, h_a, mapping, WiP, WhP, h_a, 0);
        bond_gemm_fb<<<2049, blk, 0, stream>>>(fini, h_a, mapping, WiP, WhP, h_b, 1);
        bond_gemm_fb<<<2049, blk, 0, stream>>>(fini, h_b, mapping, WiP, WhP, h_a, 1);
        atom_gemm_fb<<<1024, blk, 0, stream>>>(atomf, h_a, a2b, WoA, WoB, b_o, out);
    }
    copy_gf<<<NMOLS * (GFD / 4) / 256, blk, 0, stream>>>((const float4*)gf, out);
}